// Round 6
// baseline (790.857 us; speedup 1.0000x reference)
//
#include <hip/hip_runtime.h>
#include <hip/hip_bf16.h>

#define N_NODES 100000
#define IN_DIM 128
#define OUT_DIM 32
#define NEG_SLOPE 0.01f
#define E_DEFAULT 1600000
#define BUCKET_SHIFT 7
#define BUCKET_SIZE 128
#define NB ((N_NODES + BUCKET_SIZE - 1) / BUCKET_SIZE)   // 782
#define ECHUNK 8192

__device__ __forceinline__ float bfu2f(unsigned int u16) {
    union { unsigned int i; float f; } v;
    v.i = u16 << 16;
    return v.f;
}
__device__ __forceinline__ unsigned short f2bfu(float f) {
    union { unsigned int i; float f; } v;
    v.f = f;
    unsigned int r = v.i + 0x7fffu + ((v.i >> 16) & 1u);  // RNE
    return (unsigned short)(r >> 16);
}

// K1: z = h @ fc_w^T, 2 nodes/thread, fc_w fp32 in LDS. Stores z bf16, s_l/s_r.
// mode 1 (atomic fallback) additionally zeroes denom and out row.
__global__ __launch_bounds__(256) void k1_z_scores(
    const float* __restrict__ h,
    const float* __restrict__ fc_w,
    const float* __restrict__ attn_w,
    unsigned short* __restrict__ zbf,
    float* __restrict__ s_l,
    float* __restrict__ s_r,
    float* __restrict__ denom,
    float* __restrict__ out,
    int mode) {
    __shared__ float wlds[OUT_DIM * IN_DIM];   // 16 KB
    __shared__ float al[OUT_DIM], ar[OUT_DIM];

    const int tid = threadIdx.x;
    for (int i = tid; i < OUT_DIM * IN_DIM; i += 256) wlds[i] = fc_w[i];
    if (tid < OUT_DIM) {
        al[tid] = attn_w[tid];
        ar[tid] = attn_w[OUT_DIM + tid];
    }
    __syncthreads();

    const int n0 = blockIdx.x * 512 + tid;
    const int n1 = n0 + 256;
    const bool v1 = (n1 < N_NODES);
    if (n0 >= N_NODES) return;

    float acc0[OUT_DIM], acc1[OUT_DIM];
#pragma unroll
    for (int j = 0; j < OUT_DIM; ++j) { acc0[j] = 0.f; acc1[j] = 0.f; }

    const float4* hp0 = (const float4*)(h + (size_t)n0 * IN_DIM);
    const float4* hp1 = (const float4*)(h + (size_t)(v1 ? n1 : n0) * IN_DIM);

#pragma unroll 2
    for (int kg = 0; kg < IN_DIM / 4; ++kg) {
        const float4 ha = hp0[kg];
        const float4 hb = hp1[kg];
#pragma unroll
        for (int j = 0; j < OUT_DIM; ++j) {
            const float4 w = *(const float4*)&wlds[j * IN_DIM + kg * 4];
            acc0[j] += ha.x * w.x + ha.y * w.y + ha.z * w.z + ha.w * w.w;
            acc1[j] += hb.x * w.x + hb.y * w.y + hb.z * w.z + hb.w * w.w;
        }
    }

    for (int pass = 0; pass < 2; ++pass) {
        if (pass && !v1) break;
        const int node = pass ? n1 : n0;
        const float* acc = pass ? acc1 : acc0;
        float sl = 0.f, sr = 0.f;
#pragma unroll
        for (int j = 0; j < OUT_DIM; ++j) {
            sl += acc[j] * al[j];
            sr += acc[j] * ar[j];
        }
        s_l[node] = sl;
        s_r[node] = sr;

        uint4* zp = (uint4*)(zbf + (size_t)node * OUT_DIM);
#pragma unroll
        for (int q = 0; q < 4; ++q) {
            uint4 pk;
            pk.x = (unsigned int)f2bfu(acc[8 * q + 0]) | ((unsigned int)f2bfu(acc[8 * q + 1]) << 16);
            pk.y = (unsigned int)f2bfu(acc[8 * q + 2]) | ((unsigned int)f2bfu(acc[8 * q + 3]) << 16);
            pk.z = (unsigned int)f2bfu(acc[8 * q + 4]) | ((unsigned int)f2bfu(acc[8 * q + 5]) << 16);
            pk.w = (unsigned int)f2bfu(acc[8 * q + 6]) | ((unsigned int)f2bfu(acc[8 * q + 7]) << 16);
            zp[q] = pk;
        }

        if (mode == 1) {
            denom[node] = 0.f;
            float4* op = (float4*)(out + (size_t)node * OUT_DIM);
            const float4 zero4 = make_float4(0.f, 0.f, 0.f, 0.f);
#pragma unroll
            for (int q = 0; q < 8; ++q) op[q] = zero4;
        }
    }
}

// ---------------- bucketed CSR path ----------------

// Per-block histogram over 782 buckets; blkcnt[bin*nblk + blk].
__global__ __launch_bounds__(256) void k_hist2(
    const int* __restrict__ dst, int* __restrict__ blkcnt, int E, int nblk) {
    __shared__ int bins[NB];
    const int t = threadIdx.x;
    for (int i = t; i < NB; i += 256) bins[i] = 0;
    __syncthreads();
    const int e0 = blockIdx.x * ECHUNK;
    for (int k = 0; k < ECHUNK; k += 256) {
        const int e = e0 + k + t;
        if (e < E) atomicAdd(&bins[dst[e] >> BUCKET_SHIFT], 1);
    }
    __syncthreads();
    for (int i = t; i < NB; i += 256) blkcnt[i * nblk + blockIdx.x] = bins[i];
}

// Single block: bucket starts (exclusive scan of row sums) + in-place
// per-(bin,blk) running prefix so each block owns an exclusive range per bin.
__global__ __launch_bounds__(1024) void k_scan2(
    int* __restrict__ blkcnt, int* __restrict__ start, int E, int nblk) {
    __shared__ int sc[1024];
    const int t = threadIdx.x;
    int s = 0;
    if (t < NB) {
        for (int k = 0; k < nblk; ++k) s += blkcnt[t * nblk + k];
    }
    sc[t] = s;
    __syncthreads();
    for (int off = 1; off < 1024; off <<= 1) {
        const int u = (t >= off) ? sc[t - off] : 0;
        __syncthreads();
        sc[t] += u;
        __syncthreads();
    }
    if (t < NB) {
        int run = sc[t] - s;   // exclusive bucket start
        start[t] = run;
        for (int k = 0; k < nblk; ++k) {
            const int c = blkcnt[t * nblk + k];
            blkcnt[t * nblk + k] = run;
            run += c;
        }
    }
    if (t == 1023) start[NB] = sc[1023];
}

// Re-read edges; LDS cursors (seeded with this block's exclusive offsets);
// write packed (ldst<<17 | src) into block-exclusive contiguous runs.
__global__ __launch_bounds__(256) void k_scatter2(
    const int* __restrict__ src, const int* __restrict__ dst,
    const int* __restrict__ blkcnt, int* __restrict__ packed, int E, int nblk) {
    __shared__ int ofs[NB];
    const int t = threadIdx.x;
    for (int i = t; i < NB; i += 256) ofs[i] = blkcnt[i * nblk + blockIdx.x];
    __syncthreads();
    const int e0 = blockIdx.x * ECHUNK;
    for (int k = 0; k < ECHUNK; k += 256) {
        const int e = e0 + k + t;
        if (e < E) {
            const int d = dst[e];
            const int bin = d >> BUCKET_SHIFT;
            const int pos = atomicAdd(&ofs[bin], 1);
            packed[pos] = ((d & (BUCKET_SIZE - 1)) << 17) | src[e];
        }
    }
}

// One workgroup per bucket (128 nodes). LDS fp32 accumulators (stride 33 ->
// conflict-free banks). 16 half-waves each own an edge: broadcast packed/s_l
// reads, 64B contiguous zbf row, 32 ds_add_f32. Fused divide + store.
__global__ __launch_bounds__(512) void k_accum(
    const int* __restrict__ start,
    const int* __restrict__ packed,
    const float* __restrict__ s_l,
    const float* __restrict__ s_r,
    const unsigned short* __restrict__ zbf,
    float* __restrict__ out) {
    __shared__ float acc[BUCKET_SIZE * 33];
    __shared__ float dnm[BUCKET_SIZE];
    __shared__ float srt[BUCKET_SIZE];

    const int bin = blockIdx.x;
    const int base = bin * BUCKET_SIZE;
    const int t = threadIdx.x;

    for (int i = t; i < BUCKET_SIZE * 33; i += 512) acc[i] = 0.f;
    if (t < BUCKET_SIZE) {
        dnm[t] = 0.f;
        const int n = base + t;
        srt[t] = (n < N_NODES) ? s_r[n] : 0.f;
    }
    __syncthreads();

    const int st = start[bin];
    const int cnt = start[bin + 1] - st;
    const int slot = t >> 5;          // 16 half-wave slots
    const int dim = t & 31;

    for (int i = slot; i < cnt; i += 16) {
        const int p = packed[st + i];          // broadcast within half-wave
        const int sn = p & 0x1FFFF;
        const int ldst = p >> 17;
        float x = s_l[sn] + srt[ldst];
        x = (x > 0.f) ? x : NEG_SLOPE * x;
        const float w = __expf(x);
        const float zv = bfu2f(zbf[(size_t)sn * OUT_DIM + dim]);
        atomicAdd(&acc[ldst * 33 + dim], w * zv);
        if (dim == 0) atomicAdd(&dnm[ldst], w);
    }
    __syncthreads();

    for (int i = t; i < BUCKET_SIZE * OUT_DIM; i += 512) {
        const int ldst = i >> 5;
        const int d = i & 31;
        const int n = base + ldst;
        if (n < N_NODES) {
            const float dd = dnm[ldst];
            out[(size_t)n * OUT_DIM + d] = (dd > 0.f) ? acc[ldst * 33 + d] / dd : 0.f;
        }
    }
}

// ---------------- atomic fallback path (known-passing) ----------

__global__ __launch_bounds__(256) void k3_edges(
    const int* __restrict__ src,
    const int* __restrict__ dst,
    const float* __restrict__ s_l,
    const float* __restrict__ s_r,
    const unsigned short* __restrict__ zbf,
    float* __restrict__ denom,
    float* __restrict__ out,
    int E) {
    const long long gid = (long long)blockIdx.x * 256 + threadIdx.x;
    const int e = (int)(gid >> 3);
    const int q = (int)(gid & 7);
    if (e >= E) return;

    const int s = src[e];
    const int d = dst[e];
    float x = s_l[s] + s_r[d];
    x = (x > 0.f) ? x : NEG_SLOPE * x;
    const float w = __expf(x);

    const uint2 zv = *(const uint2*)&zbf[(size_t)s * OUT_DIM + q * 4];
    float* op = &out[(size_t)d * OUT_DIM + q * 4];
    unsafeAtomicAdd(op + 0, w * bfu2f(zv.x & 0xffffu));
    unsafeAtomicAdd(op + 1, w * bfu2f(zv.x >> 16));
    unsafeAtomicAdd(op + 2, w * bfu2f(zv.y & 0xffffu));
    unsafeAtomicAdd(op + 3, w * bfu2f(zv.y >> 16));
    if (q == 0) unsafeAtomicAdd(&denom[d], w);
}

__global__ __launch_bounds__(256) void k4_finalize(
    const float* __restrict__ denom, float* __restrict__ out) {
    const int i = blockIdx.x * 256 + threadIdx.x;
    if (i >= N_NODES * OUT_DIM) return;
    const float dnm = denom[i >> 5];
    out[i] = (dnm > 0.f) ? out[i] / dnm : 0.f;
}

extern "C" void kernel_launch(void* const* d_in, const int* in_sizes, int n_in,
                              void* d_out, int out_size, void* d_ws, size_t ws_size,
                              hipStream_t stream) {
    const float* h      = (const float*)d_in[0];
    const int*   src    = (const int*)d_in[1];
    const int*   dst    = (const int*)d_in[2];
    const float* fc_w   = (const float*)d_in[3];
    const float* attn_w = (const float*)d_in[4];
    float* out = (float*)d_out;
    const int E = (in_sizes[1] > 0) ? in_sizes[1] : E_DEFAULT;
    const int nblk = (E + ECHUNK - 1) / ECHUNK;

    char* ws = (char*)d_ws;
    size_t off = 0;
    unsigned short* zbf = (unsigned short*)(ws + off);
    off += (size_t)N_NODES * OUT_DIM * sizeof(unsigned short);      // 6.4 MB
    float* s_l = (float*)(ws + off); off += (size_t)N_NODES * 4;    // 0.4 MB
    float* s_r = (float*)(ws + off); off += (size_t)N_NODES * 4;    // 0.4 MB

    const size_t base = off;
    int* packed = (int*)(ws + off);  off += (size_t)E * 4;          // 6.4 MB
    int* blkcnt = (int*)(ws + off);  off += (size_t)NB * nblk * 4;  // ~0.6 MB
    int* start  = (int*)(ws + off);  off += ((size_t)NB + 1) * 4;
    const size_t csr_total = off;
    float* denom = (float*)(ws + base);   // fallback aliases CSR region

    const bool use_csr = (ws_size >= csr_total);
    const int blocks_k1 = (N_NODES + 511) / 512;

    if (use_csr) {
        k1_z_scores<<<blocks_k1, 256, 0, stream>>>(h, fc_w, attn_w, zbf, s_l, s_r,
                                                   nullptr, nullptr, 0);
        k_hist2<<<nblk, 256, 0, stream>>>(dst, blkcnt, E, nblk);
        k_scan2<<<1, 1024, 0, stream>>>(blkcnt, start, E, nblk);
        k_scatter2<<<nblk, 256, 0, stream>>>(src, dst, blkcnt, packed, E, nblk);
        k_accum<<<NB, 512, 0, stream>>>(start, packed, s_l, s_r, zbf, out);
    } else {
        k1_z_scores<<<blocks_k1, 256, 0, stream>>>(h, fc_w, attn_w, zbf, s_l, s_r,
                                                   denom, out, 1);
        const long long tot = (long long)E * 8;
        const int blocks_k3 = (int)((tot + 255) / 256);
        k3_edges<<<blocks_k3, 256, 0, stream>>>(src, dst, s_l, s_r, zbf, denom, out, E);
        const int blocks_k4 = (N_NODES * OUT_DIM + 255) / 256;
        k4_finalize<<<blocks_k4, 256, 0, stream>>>(denom, out);
    }
}

// Round 7
// 266.528 us; speedup vs baseline: 2.9673x; 2.9673x over previous
//
#include <hip/hip_runtime.h>
#include <hip/hip_bf16.h>

#define N_NODES 100000
#define IN_DIM 128
#define OUT_DIM 32
#define NEG_SLOPE 0.01f
#define E_DEFAULT 1600000
#define BUCKET_SHIFT 7
#define BUCKET_SIZE 128
#define NB ((N_NODES + BUCKET_SIZE - 1) / BUCKET_SIZE)   // 782
#define NBP 800                                          // padded bin stride
#define ECHUNK 8192
#define PCAP 8192   // max edges staged per bucket (mean 2046, sd ~45 -> safe)

__device__ __forceinline__ float bfu2f(unsigned int u16) {
    union { unsigned int i; float f; } v;
    v.i = u16 << 16;
    return v.f;
}
__device__ __forceinline__ unsigned short f2bfu(float f) {
    union { unsigned int i; float f; } v;
    v.f = f;
    unsigned int r = v.i + 0x7fffu + ((v.i >> 16) & 1u);  // RNE
    return (unsigned short)(r >> 16);
}

// K1: z = h @ fc_w^T, 2 nodes/thread, fc_w fp32 in LDS. Stores z bf16, s_l/s_r.
// mode 1 (atomic fallback) additionally zeroes denom and out row.
__global__ __launch_bounds__(256) void k1_z_scores(
    const float* __restrict__ h,
    const float* __restrict__ fc_w,
    const float* __restrict__ attn_w,
    unsigned short* __restrict__ zbf,
    float* __restrict__ s_l,
    float* __restrict__ s_r,
    float* __restrict__ denom,
    float* __restrict__ out,
    int mode) {
    __shared__ float wlds[OUT_DIM * IN_DIM];   // 16 KB
    __shared__ float al[OUT_DIM], ar[OUT_DIM];

    const int tid = threadIdx.x;
    for (int i = tid; i < OUT_DIM * IN_DIM; i += 256) wlds[i] = fc_w[i];
    if (tid < OUT_DIM) {
        al[tid] = attn_w[tid];
        ar[tid] = attn_w[OUT_DIM + tid];
    }
    __syncthreads();

    const int n0 = blockIdx.x * 512 + tid;
    const int n1 = n0 + 256;
    const bool v1 = (n1 < N_NODES);
    if (n0 >= N_NODES) return;

    float acc0[OUT_DIM], acc1[OUT_DIM];
#pragma unroll
    for (int j = 0; j < OUT_DIM; ++j) { acc0[j] = 0.f; acc1[j] = 0.f; }

    const float4* hp0 = (const float4*)(h + (size_t)n0 * IN_DIM);
    const float4* hp1 = (const float4*)(h + (size_t)(v1 ? n1 : n0) * IN_DIM);

#pragma unroll 2
    for (int kg = 0; kg < IN_DIM / 4; ++kg) {
        const float4 ha = hp0[kg];
        const float4 hb = hp1[kg];
#pragma unroll
        for (int j = 0; j < OUT_DIM; ++j) {
            const float4 w = *(const float4*)&wlds[j * IN_DIM + kg * 4];
            acc0[j] += ha.x * w.x + ha.y * w.y + ha.z * w.z + ha.w * w.w;
            acc1[j] += hb.x * w.x + hb.y * w.y + hb.z * w.z + hb.w * w.w;
        }
    }

    for (int pass = 0; pass < 2; ++pass) {
        if (pass && !v1) break;
        const int node = pass ? n1 : n0;
        const float* acc = pass ? acc1 : acc0;
        float sl = 0.f, sr = 0.f;
#pragma unroll
        for (int j = 0; j < OUT_DIM; ++j) {
            sl += acc[j] * al[j];
            sr += acc[j] * ar[j];
        }
        s_l[node] = sl;
        s_r[node] = sr;

        uint4* zp = (uint4*)(zbf + (size_t)node * OUT_DIM);
#pragma unroll
        for (int q = 0; q < 4; ++q) {
            uint4 pk;
            pk.x = (unsigned int)f2bfu(acc[8 * q + 0]) | ((unsigned int)f2bfu(acc[8 * q + 1]) << 16);
            pk.y = (unsigned int)f2bfu(acc[8 * q + 2]) | ((unsigned int)f2bfu(acc[8 * q + 3]) << 16);
            pk.z = (unsigned int)f2bfu(acc[8 * q + 4]) | ((unsigned int)f2bfu(acc[8 * q + 5]) << 16);
            pk.w = (unsigned int)f2bfu(acc[8 * q + 6]) | ((unsigned int)f2bfu(acc[8 * q + 7]) << 16);
            zp[q] = pk;
        }

        if (mode == 1) {
            denom[node] = 0.f;
            float4* op = (float4*)(out + (size_t)node * OUT_DIM);
            const float4 zero4 = make_float4(0.f, 0.f, 0.f, 0.f);
#pragma unroll
            for (int q = 0; q < 8; ++q) op[q] = zero4;
        }
    }
}

// ---------------- bucket-sort pipeline ----------------

// Per-edge-block histogram over NB buckets; blkcnt[blk*NBP + bin] (coalesced).
__global__ __launch_bounds__(256) void k_hist2(
    const int* __restrict__ dst, int* __restrict__ blkcnt, int E) {
    __shared__ int bins[NB];
    const int t = threadIdx.x;
    for (int i = t; i < NB; i += 256) bins[i] = 0;
    __syncthreads();
    const int e0 = blockIdx.x * ECHUNK;
    for (int k = 0; k < ECHUNK; k += 256) {
        const int e = e0 + k + t;
        if (e < E) atomicAdd(&bins[dst[e] >> BUCKET_SHIFT], 1);
    }
    __syncthreads();
    int* row = blkcnt + (size_t)blockIdx.x * NBP;
    for (int i = t; i < NB; i += 256) row[i] = bins[i];
}

// 1 block: bucket starts + per-(bin,blk) exclusive offsets. All accesses
// coalesced across threads (thread t = bin t, walking blk-major rows).
__global__ __launch_bounds__(1024) void k_scan2(
    int* __restrict__ blkcnt, int* __restrict__ bstart, int nblk) {
    __shared__ int sc[1024];
    const int t = threadIdx.x;
    int s = 0;
    if (t < NB) {
        for (int k = 0; k < nblk; ++k) s += blkcnt[(size_t)k * NBP + t];
    }
    sc[t] = s;
    __syncthreads();
    for (int off = 1; off < 1024; off <<= 1) {
        const int u = (t >= off) ? sc[t - off] : 0;
        __syncthreads();
        sc[t] += u;
        __syncthreads();
    }
    if (t < NB) {
        int run = sc[t] - s;
        bstart[t] = run;
        for (int k = 0; k < nblk; ++k) {
            const int c = blkcnt[(size_t)k * NBP + t];
            blkcnt[(size_t)k * NBP + t] = run;
            run += c;
        }
    }
    if (t == 1023) bstart[NB] = sc[1023];
}

// Edges -> packed {ldst:7|src:17} into block-exclusive bucket runs (LDS
// cursors, plain stores; L2 merges short runs -> low write amplification).
__global__ __launch_bounds__(256) void k_scatter2(
    const int* __restrict__ src, const int* __restrict__ dst,
    const int* __restrict__ blkcnt, int* __restrict__ packed, int E) {
    __shared__ int ofs[NB];
    const int t = threadIdx.x;
    const int* row = blkcnt + (size_t)blockIdx.x * NBP;
    for (int i = t; i < NB; i += 256) ofs[i] = row[i];
    __syncthreads();
    const int e0 = blockIdx.x * ECHUNK;
    for (int k = 0; k < ECHUNK; k += 256) {
        const int e = e0 + k + t;
        if (e < E) {
            const int d = dst[e];
            const int bin = d >> BUCKET_SHIFT;
            const int pos = atomicAdd(&ofs[bin], 1);
            packed[pos] = ((d & (BUCKET_SIZE - 1)) << 17) | src[e];
        }
    }
}

// One block per bucket: stage packed entries in LDS, per-node count + scan ->
// fine node starts (nstart), then in-place permute to node-sorted esrc.
__global__ __launch_bounds__(256) void k_place(
    const int* __restrict__ bstart,
    int* __restrict__ packed,           // in: bucket-sorted; out: node-sorted src
    int* __restrict__ nstart) {
    __shared__ int pk[PCAP];
    __shared__ int cnt128[BUCKET_SIZE];
    __shared__ int pref[BUCKET_SIZE];
    __shared__ int cur[BUCKET_SIZE];

    const int bin = blockIdx.x;
    const int st = bstart[bin];
    int cnt = bstart[bin + 1] - st;
    if (cnt > PCAP) cnt = PCAP;   // unreachable for this input distribution
    const int t = threadIdx.x;

    if (t < BUCKET_SIZE) cnt128[t] = 0;
    __syncthreads();
    for (int i = t; i < cnt; i += 256) {
        const int p = packed[st + i];
        pk[i] = p;
        atomicAdd(&cnt128[p >> 17], 1);
    }
    __syncthreads();
    if (t < BUCKET_SIZE) pref[t] = cnt128[t];
    __syncthreads();
    for (int off = 1; off < BUCKET_SIZE; off <<= 1) {
        int u = 0;
        if (t < BUCKET_SIZE && t >= off) u = pref[t - off];
        __syncthreads();
        if (t < BUCKET_SIZE) pref[t] += u;
        __syncthreads();
    }
    if (t < BUCKET_SIZE) {
        const int excl = pref[t] - cnt128[t];
        nstart[bin * BUCKET_SIZE + t] = st + excl;
        cur[t] = excl;
    }
    __syncthreads();
    for (int i = t; i < cnt; i += 256) {
        const int p = pk[i];
        const int pos = st + atomicAdd(&cur[p >> 17], 1);
        packed[pos] = p & 0x1FFFF;
    }
}

// One wave per node: 8 edge streams x 8 dim-groups (4 dims/lane, uint2 loads).
// Chain depth ~= deg/8 ~= 2. Butterfly-reduce over stream bits, fused divide.
__global__ __launch_bounds__(256) void k_gather8(
    const int* __restrict__ nstart,
    const int* __restrict__ esrc,
    const float* __restrict__ s_l,
    const float* __restrict__ s_r,
    const unsigned short* __restrict__ zbf,
    float* __restrict__ out) {
    const int gtid = blockIdx.x * 256 + threadIdx.x;
    const int n = gtid >> 6;
    if (n >= N_NODES) return;
    const int lane = gtid & 63;
    const int eslot = lane >> 3;
    const int dimg = lane & 7;

    const int st = nstart[n];
    const int cnt = nstart[n + 1] - st;
    const float sr_n = s_r[n];

    float a0 = 0.f, a1 = 0.f, a2 = 0.f, a3 = 0.f, dn = 0.f;
    for (int i = eslot; i < cnt; i += 8) {
        const int es = esrc[st + i];
        float x = s_l[es] + sr_n;
        x = (x > 0.f) ? x : NEG_SLOPE * x;
        const float w = __expf(x);
        const uint2 zv = *(const uint2*)&zbf[(size_t)es * OUT_DIM + dimg * 4];
        a0 += w * bfu2f(zv.x & 0xffffu);
        a1 += w * bfu2f(zv.x >> 16);
        a2 += w * bfu2f(zv.y & 0xffffu);
        a3 += w * bfu2f(zv.y >> 16);
        dn += w;
    }
#pragma unroll
    for (int m = 8; m < 64; m <<= 1) {
        a0 += __shfl_xor(a0, m, 64);
        a1 += __shfl_xor(a1, m, 64);
        a2 += __shfl_xor(a2, m, 64);
        a3 += __shfl_xor(a3, m, 64);
        dn += __shfl_xor(dn, m, 64);
    }
    if (eslot == 0) {
        const float inv = (dn > 0.f) ? 1.f / dn : 0.f;
        *(float4*)&out[(size_t)n * OUT_DIM + dimg * 4] =
            make_float4(a0 * inv, a1 * inv, a2 * inv, a3 * inv);
    }
}

// ---------------- atomic fallback path (known-passing) ----------

__global__ __launch_bounds__(256) void k3_edges(
    const int* __restrict__ src,
    const int* __restrict__ dst,
    const float* __restrict__ s_l,
    const float* __restrict__ s_r,
    const unsigned short* __restrict__ zbf,
    float* __restrict__ denom,
    float* __restrict__ out,
    int E) {
    const long long gid = (long long)blockIdx.x * 256 + threadIdx.x;
    const int e = (int)(gid >> 3);
    const int q = (int)(gid & 7);
    if (e >= E) return;

    const int s = src[e];
    const int d = dst[e];
    float x = s_l[s] + s_r[d];
    x = (x > 0.f) ? x : NEG_SLOPE * x;
    const float w = __expf(x);

    const uint2 zv = *(const uint2*)&zbf[(size_t)s * OUT_DIM + q * 4];
    float* op = &out[(size_t)d * OUT_DIM + q * 4];
    unsafeAtomicAdd(op + 0, w * bfu2f(zv.x & 0xffffu));
    unsafeAtomicAdd(op + 1, w * bfu2f(zv.x >> 16));
    unsafeAtomicAdd(op + 2, w * bfu2f(zv.y & 0xffffu));
    unsafeAtomicAdd(op + 3, w * bfu2f(zv.y >> 16));
    if (q == 0) unsafeAtomicAdd(&denom[d], w);
}

__global__ __launch_bounds__(256) void k4_finalize(
    const float* __restrict__ denom, float* __restrict__ out) {
    const int i = blockIdx.x * 256 + threadIdx.x;
    if (i >= N_NODES * OUT_DIM) return;
    const float dnm = denom[i >> 5];
    out[i] = (dnm > 0.f) ? out[i] / dnm : 0.f;
}

extern "C" void kernel_launch(void* const* d_in, const int* in_sizes, int n_in,
                              void* d_out, int out_size, void* d_ws, size_t ws_size,
                              hipStream_t stream) {
    const float* h      = (const float*)d_in[0];
    const int*   src    = (const int*)d_in[1];
    const int*   dst    = (const int*)d_in[2];
    const float* fc_w   = (const float*)d_in[3];
    const float* attn_w = (const float*)d_in[4];
    float* out = (float*)d_out;
    const int E = (in_sizes[1] > 0) ? in_sizes[1] : E_DEFAULT;
    const int nblk = (E + ECHUNK - 1) / ECHUNK;

    char* ws = (char*)d_ws;
    size_t off = 0;
    unsigned short* zbf = (unsigned short*)(ws + off);
    off += (size_t)N_NODES * OUT_DIM * sizeof(unsigned short);       // 6.4 MB
    float* s_l = (float*)(ws + off); off += (size_t)N_NODES * 4;     // 0.4 MB
    float* s_r = (float*)(ws + off); off += (size_t)N_NODES * 4;     // 0.4 MB

    const size_t base = off;
    int* packed = (int*)(ws + off);  off += (size_t)E * 4;           // 6.4 MB
    int* blkcnt = (int*)(ws + off);  off += (size_t)nblk * NBP * 4;  // 0.63 MB
    int* bstart = (int*)(ws + off);  off += ((size_t)NB + 1) * 4;
    int* nstart = (int*)(ws + off);  off += ((size_t)NB * BUCKET_SIZE + 1) * 4;  // 0.4 MB
    const size_t csr_total = off;    // ~14.7 MB
    float* denom = (float*)(ws + base);   // fallback aliases sort region

    const bool use_csr = (ws_size >= csr_total);
    const int blocks_k1 = (N_NODES + 511) / 512;

    if (use_csr) {
        k1_z_scores<<<blocks_k1, 256, 0, stream>>>(h, fc_w, attn_w, zbf, s_l, s_r,
                                                   nullptr, nullptr, 0);
        k_hist2<<<nblk, 256, 0, stream>>>(dst, blkcnt, E);
        k_scan2<<<1, 1024, 0, stream>>>(blkcnt, bstart, nblk);
        k_scatter2<<<nblk, 256, 0, stream>>>(src, dst, blkcnt, packed, E);
        k_place<<<NB, 256, 0, stream>>>(bstart, packed, nstart);
        const int blocks_g = (N_NODES * 64 + 255) / 256;
        k_gather8<<<blocks_g, 256, 0, stream>>>(nstart, packed, s_l, s_r, zbf, out);
    } else {
        k1_z_scores<<<blocks_k1, 256, 0, stream>>>(h, fc_w, attn_w, zbf, s_l, s_r,
                                                   denom, out, 1);
        const long long tot = (long long)E * 8;
        const int blocks_k3 = (int)((tot + 255) / 256);
        k3_edges<<<blocks_k3, 256, 0, stream>>>(src, dst, s_l, s_r, zbf, denom, out, E);
        const int blocks_k4 = (N_NODES * OUT_DIM + 255) / 256;
        k4_finalize<<<blocks_k4, 256, 0, stream>>>(denom, out);
    }
}

// Round 8
// 212.425 us; speedup vs baseline: 3.7230x; 1.2547x over previous
//
#include <hip/hip_runtime.h>
#include <hip/hip_bf16.h>

#define N_NODES 100000
#define IN_DIM 128
#define OUT_DIM 32
#define NEG_SLOPE 0.01f
#define E_DEFAULT 1600000
#define BUCKET_SHIFT 7
#define BUCKET_SIZE 128
#define NB ((N_NODES + BUCKET_SIZE - 1) / BUCKET_SIZE)   // 782
#define ECHUNK 8192
#define PCAP 8192
#define WPAD 136   // bf16 LDS row stride for fc_w (16B-aligned, bank-balanced)

typedef __attribute__((ext_vector_type(8))) short bf16x8;
typedef __attribute__((ext_vector_type(4))) float f32x4;

__device__ __forceinline__ float bfu2f(unsigned int u16) {
    union { unsigned int i; float f; } v;
    v.i = u16 << 16;
    return v.f;
}
__device__ __forceinline__ unsigned short f2bfu(float f) {
    union { unsigned int i; float f; } v;
    v.f = f;
    unsigned int r = v.i + 0x7fffu + ((v.i >> 16) & 1u);  // RNE
    return (unsigned short)(r >> 16);
}

// K1 (MFMA): z = h @ fc_w^T. One wave = 16 nodes x 32 dims, K=128.
// A: h rows cast fp32->bf16 in-reg, layout A[m=lane&15][k=(lane>>4)*8+j].
// B: fc_w staged bf16 in LDS (row stride WPAD), B[k][n]: n=lane&15(+16).
// C/D: col=lane&15, row=(lane>>4)*4+reg (verified mapping).
// Also: s_l/s_r via quad shfl-reduce; block 0 zeroes bsum (runs before hist).
__global__ __launch_bounds__(256) void k1_mfma(
    const float* __restrict__ h,
    const float* __restrict__ fc_w,
    const float* __restrict__ attn_w,
    unsigned short* __restrict__ zbf,
    float* __restrict__ s_l,
    float* __restrict__ s_r,
    int* __restrict__ bsum) {
    __shared__ unsigned short wlds[OUT_DIM * WPAD];  // 8.5 KB bf16
    __shared__ float al[OUT_DIM], ar[OUT_DIM];

    const int t = threadIdx.x;
    if (blockIdx.x == 0) {
        for (int i = t; i < NB; i += 256) bsum[i] = 0;
    }
    // stage fc_w (32x128 fp32) -> bf16 LDS, padded rows
    for (int i = t; i < OUT_DIM * IN_DIM / 4; i += 256) {
        const float4 v = ((const float4*)fc_w)[i];
        const int idx = i * 4;
        const int row = idx >> 7, col = idx & 127;
        unsigned short* p = &wlds[row * WPAD + col];
        p[0] = f2bfu(v.x); p[1] = f2bfu(v.y); p[2] = f2bfu(v.z); p[3] = f2bfu(v.w);
    }
    if (t < 2 * OUT_DIM) {
        if (t < OUT_DIM) al[t] = attn_w[t];
        else ar[t - OUT_DIM] = attn_w[t];
    }
    __syncthreads();

    const int wid = (blockIdx.x * 256 + t) >> 6;
    const int base = wid * 16;
    if (base >= N_NODES) return;
    const int lane = t & 63;
    const int row16 = lane & 15;
    const int quad = lane >> 4;

    f32x4 acc0 = {0.f, 0.f, 0.f, 0.f};
    f32x4 acc1 = {0.f, 0.f, 0.f, 0.f};
    const float* hrow = h + (size_t)(base + row16) * IN_DIM + quad * 8;
    const unsigned short* b0 = &wlds[row16 * WPAD + quad * 8];
    const unsigned short* b1 = &wlds[(row16 + 16) * WPAD + quad * 8];

#pragma unroll
    for (int s = 0; s < 4; ++s) {
        const float4 a0 = *(const float4*)(hrow + s * 32);
        const float4 a1 = *(const float4*)(hrow + s * 32 + 4);
        bf16x8 af;
        af[0] = (short)f2bfu(a0.x); af[1] = (short)f2bfu(a0.y);
        af[2] = (short)f2bfu(a0.z); af[3] = (short)f2bfu(a0.w);
        af[4] = (short)f2bfu(a1.x); af[5] = (short)f2bfu(a1.y);
        af[6] = (short)f2bfu(a1.z); af[7] = (short)f2bfu(a1.w);
        const bf16x8 bf0 = *(const bf16x8*)(b0 + s * 32);
        const bf16x8 bf1 = *(const bf16x8*)(b1 + s * 32);
        acc0 = __builtin_amdgcn_mfma_f32_16x16x32_bf16(af, bf0, acc0, 0, 0, 0);
        acc1 = __builtin_amdgcn_mfma_f32_16x16x32_bf16(af, bf1, acc1, 0, 0, 0);
    }

    const float al_lo = al[row16], al_hi = al[row16 + 16];
    const float ar_lo = ar[row16], ar_hi = ar[row16 + 16];
#pragma unroll
    for (int r = 0; r < 4; ++r) {
        const int node = base + quad * 4 + r;
        float p = acc0[r] * al_lo + acc1[r] * al_hi;
        float q = acc0[r] * ar_lo + acc1[r] * ar_hi;
        p += __shfl_xor(p, 1, 64); p += __shfl_xor(p, 2, 64);
        p += __shfl_xor(p, 4, 64); p += __shfl_xor(p, 8, 64);
        q += __shfl_xor(q, 1, 64); q += __shfl_xor(q, 2, 64);
        q += __shfl_xor(q, 4, 64); q += __shfl_xor(q, 8, 64);
        if (row16 == 0) { s_l[node] = p; s_r[node] = q; }
        zbf[(size_t)node * OUT_DIM + row16] = f2bfu(acc0[r]);
        zbf[(size_t)node * OUT_DIM + 16 + row16] = f2bfu(acc1[r]);
    }
}

// ---------------- bucket-sort pipeline ----------------

// Per-edge-block histogram; blkcnt[bin*nblkp + blk]; bucket totals via atomics.
__global__ __launch_bounds__(256) void k_hist2(
    const int* __restrict__ dst, int* __restrict__ blkcnt,
    int* __restrict__ bsum, int E, int nblkp) {
    __shared__ int bins[NB];
    const int t = threadIdx.x;
    for (int i = t; i < NB; i += 256) bins[i] = 0;
    __syncthreads();
    const int e0 = blockIdx.x * ECHUNK;
    for (int k = 0; k < ECHUNK; k += 256) {
        const int e = e0 + k + t;
        if (e < E) atomicAdd(&bins[dst[e] >> BUCKET_SHIFT], 1);
    }
    __syncthreads();
    for (int i = t; i < NB; i += 256) {
        const int c = bins[i];
        blkcnt[(size_t)i * nblkp + blockIdx.x] = c;
        if (c) atomicAdd(&bsum[i], c);
    }
}

// 1 small block: exclusive scan over 782 bucket totals -> bstart.
__global__ __launch_bounds__(1024) void k_scan_top(
    const int* __restrict__ bsum, int* __restrict__ bstart) {
    __shared__ int sc[1024];
    const int t = threadIdx.x;
    const int v = (t < NB) ? bsum[t] : 0;
    sc[t] = v;
    __syncthreads();
    for (int off = 1; off < 1024; off <<= 1) {
        const int u = (t >= off) ? sc[t - off] : 0;
        __syncthreads();
        sc[t] += u;
        __syncthreads();
    }
    if (t < NB) bstart[t] = sc[t] - v;
    if (t == 1023) bstart[NB] = sc[1023];
}

// One wave per bin: coalesced row read, wave-scan (shfl_up), writeback of
// per-(bin,blk) exclusive global offsets.
__global__ __launch_bounds__(256) void k_scan_cols(
    int* __restrict__ blkcnt, const int* __restrict__ bstart,
    int nblk, int nblkp) {
    const int bin = blockIdx.x * 4 + (threadIdx.x >> 6);
    if (bin >= NB) return;
    const int lane = threadIdx.x & 63;
    const int c = (nblk + 63) >> 6;
    const int k0 = lane * c;
    int* rowp = blkcnt + (size_t)bin * nblkp;
    int s = 0;
    for (int j = 0; j < c; ++j) {
        const int k = k0 + j;
        if (k < nblk) s += rowp[k];
    }
    int incl = s;
    for (int off = 1; off < 64; off <<= 1) {
        const int u = __shfl_up(incl, off, 64);
        if (lane >= off) incl += u;
    }
    int run = bstart[bin] + incl - s;
    for (int j = 0; j < c; ++j) {
        const int k = k0 + j;
        if (k < nblk) {
            const int v = rowp[k];
            rowp[k] = run;
            run += v;
        }
    }
}

// Edges -> packed {ldst:7|src:17} into block-exclusive bucket runs.
__global__ __launch_bounds__(256) void k_scatter2(
    const int* __restrict__ src, const int* __restrict__ dst,
    const int* __restrict__ blkcnt, int* __restrict__ packed, int E, int nblkp) {
    __shared__ int ofs[NB];
    const int t = threadIdx.x;
    for (int i = t; i < NB; i += 256) ofs[i] = blkcnt[(size_t)i * nblkp + blockIdx.x];
    __syncthreads();
    const int e0 = blockIdx.x * ECHUNK;
    for (int k = 0; k < ECHUNK; k += 256) {
        const int e = e0 + k + t;
        if (e < E) {
            const int d = dst[e];
            const int bin = d >> BUCKET_SHIFT;
            const int pos = atomicAdd(&ofs[bin], 1);
            packed[pos] = ((d & (BUCKET_SIZE - 1)) << 17) | src[e];
        }
    }
}

// One block per bucket: stage in LDS, per-node count + scan -> nstart, then
// in-place permute to node-sorted src.
__global__ __launch_bounds__(256) void k_place(
    const int* __restrict__ bstart,
    int* __restrict__ packed,
    int* __restrict__ nstart) {
    __shared__ int pk[PCAP];
    __shared__ int cnt128[BUCKET_SIZE];
    __shared__ int pref[BUCKET_SIZE];
    __shared__ int cur[BUCKET_SIZE];

    const int bin = blockIdx.x;
    const int st = bstart[bin];
    int cnt = bstart[bin + 1] - st;
    if (cnt > PCAP) cnt = PCAP;
    const int t = threadIdx.x;

    if (t < BUCKET_SIZE) cnt128[t] = 0;
    __syncthreads();
    for (int i = t; i < cnt; i += 256) {
        const int p = packed[st + i];
        pk[i] = p;
        atomicAdd(&cnt128[p >> 17], 1);
    }
    __syncthreads();
    if (t < BUCKET_SIZE) pref[t] = cnt128[t];
    __syncthreads();
    for (int off = 1; off < BUCKET_SIZE; off <<= 1) {
        int u = 0;
        if (t < BUCKET_SIZE && t >= off) u = pref[t - off];
        __syncthreads();
        if (t < BUCKET_SIZE) pref[t] += u;
        __syncthreads();
    }
    if (t < BUCKET_SIZE) {
        const int excl = pref[t] - cnt128[t];
        nstart[bin * BUCKET_SIZE + t] = st + excl;
        cur[t] = excl;
    }
    __syncthreads();
    for (int i = t; i < cnt; i += 256) {
        const int p = pk[i];
        const int pos = st + atomicAdd(&cur[p >> 17], 1);
        packed[pos] = p & 0x1FFFF;
    }
}

// One wave per node: 8 edge streams x 8 dim-groups; butterfly-reduce; fused /denom.
__global__ __launch_bounds__(256) void k_gather8(
    const int* __restrict__ nstart,
    const int* __restrict__ esrc,
    const float* __restrict__ s_l,
    const float* __restrict__ s_r,
    const unsigned short* __restrict__ zbf,
    float* __restrict__ out) {
    const int gtid = blockIdx.x * 256 + threadIdx.x;
    const int n = gtid >> 6;
    if (n >= N_NODES) return;
    const int lane = gtid & 63;
    const int eslot = lane >> 3;
    const int dimg = lane & 7;

    const int st = nstart[n];
    const int cnt = nstart[n + 1] - st;
    const float sr_n = s_r[n];

    float a0 = 0.f, a1 = 0.f, a2 = 0.f, a3 = 0.f, dn = 0.f;
    for (int i = eslot; i < cnt; i += 8) {
        const int es = esrc[st + i];
        float x = s_l[es] + sr_n;
        x = (x > 0.f) ? x : NEG_SLOPE * x;
        const float w = __expf(x);
        const uint2 zv = *(const uint2*)&zbf[(size_t)es * OUT_DIM + dimg * 4];
        a0 += w * bfu2f(zv.x & 0xffffu);
        a1 += w * bfu2f(zv.x >> 16);
        a2 += w * bfu2f(zv.y & 0xffffu);
        a3 += w * bfu2f(zv.y >> 16);
        dn += w;
    }
#pragma unroll
    for (int m = 8; m < 64; m <<= 1) {
        a0 += __shfl_xor(a0, m, 64);
        a1 += __shfl_xor(a1, m, 64);
        a2 += __shfl_xor(a2, m, 64);
        a3 += __shfl_xor(a3, m, 64);
        dn += __shfl_xor(dn, m, 64);
    }
    if (eslot == 0) {
        const float inv = (dn > 0.f) ? 1.f / dn : 0.f;
        *(float4*)&out[(size_t)n * OUT_DIM + dimg * 4] =
            make_float4(a0 * inv, a1 * inv, a2 * inv, a3 * inv);
    }
}

// ---------------- atomic fallback path (known-passing) ----------

__global__ __launch_bounds__(256) void k1_z_scores(
    const float* __restrict__ h,
    const float* __restrict__ fc_w,
    const float* __restrict__ attn_w,
    unsigned short* __restrict__ zbf,
    float* __restrict__ s_l,
    float* __restrict__ s_r,
    float* __restrict__ denom,
    float* __restrict__ out) {
    __shared__ float wlds[OUT_DIM * IN_DIM];
    __shared__ float al[OUT_DIM], ar[OUT_DIM];

    const int tid = threadIdx.x;
    for (int i = tid; i < OUT_DIM * IN_DIM; i += 256) wlds[i] = fc_w[i];
    if (tid < OUT_DIM) {
        al[tid] = attn_w[tid];
        ar[tid] = attn_w[OUT_DIM + tid];
    }
    __syncthreads();

    const int node = blockIdx.x * 256 + tid;
    if (node >= N_NODES) return;

    float acc[OUT_DIM];
#pragma unroll
    for (int j = 0; j < OUT_DIM; ++j) acc[j] = 0.f;
    const float4* hp = (const float4*)(h + (size_t)node * IN_DIM);
#pragma unroll 4
    for (int kg = 0; kg < IN_DIM / 4; ++kg) {
        const float4 hv = hp[kg];
#pragma unroll
        for (int j = 0; j < OUT_DIM; ++j) {
            const float4 w = *(const float4*)&wlds[j * IN_DIM + kg * 4];
            acc[j] += hv.x * w.x + hv.y * w.y + hv.z * w.z + hv.w * w.w;
        }
    }
    float sl = 0.f, sr = 0.f;
#pragma unroll
    for (int j = 0; j < OUT_DIM; ++j) { sl += acc[j] * al[j]; sr += acc[j] * ar[j]; }
    s_l[node] = sl; s_r[node] = sr; denom[node] = 0.f;
    uint4* zp = (uint4*)(zbf + (size_t)node * OUT_DIM);
#pragma unroll
    for (int q = 0; q < 4; ++q) {
        uint4 pk;
        pk.x = (unsigned int)f2bfu(acc[8 * q + 0]) | ((unsigned int)f2bfu(acc[8 * q + 1]) << 16);
        pk.y = (unsigned int)f2bfu(acc[8 * q + 2]) | ((unsigned int)f2bfu(acc[8 * q + 3]) << 16);
        pk.z = (unsigned int)f2bfu(acc[8 * q + 4]) | ((unsigned int)f2bfu(acc[8 * q + 5]) << 16);
        pk.w = (unsigned int)f2bfu(acc[8 * q + 6]) | ((unsigned int)f2bfu(acc[8 * q + 7]) << 16);
        zp[q] = pk;
    }
    float4* op = (float4*)(out + (size_t)node * OUT_DIM);
    const float4 zero4 = make_float4(0.f, 0.f, 0.f, 0.f);
#pragma unroll
    for (int q = 0; q < 8; ++q) op[q] = zero4;
}

__global__ __launch_bounds__(256) void k3_edges(
    const int* __restrict__ src, const int* __restrict__ dst,
    const float* __restrict__ s_l, const float* __restrict__ s_r,
    const unsigned short* __restrict__ zbf,
    float* __restrict__ denom, float* __restrict__ out, int E) {
    const long long gid = (long long)blockIdx.x * 256 + threadIdx.x;
    const int e = (int)(gid >> 3);
    const int q = (int)(gid & 7);
    if (e >= E) return;
    const int s = src[e];
    const int d = dst[e];
    float x = s_l[s] + s_r[d];
    x = (x > 0.f) ? x : NEG_SLOPE * x;
    const float w = __expf(x);
    const uint2 zv = *(const uint2*)&zbf[(size_t)s * OUT_DIM + q * 4];
    float* op = &out[(size_t)d * OUT_DIM + q * 4];
    unsafeAtomicAdd(op + 0, w * bfu2f(zv.x & 0xffffu));
    unsafeAtomicAdd(op + 1, w * bfu2f(zv.x >> 16));
    unsafeAtomicAdd(op + 2, w * bfu2f(zv.y & 0xffffu));
    unsafeAtomicAdd(op + 3, w * bfu2f(zv.y >> 16));
    if (q == 0) unsafeAtomicAdd(&denom[d], w);
}

__global__ __launch_bounds__(256) void k4_finalize(
    const float* __restrict__ denom, float* __restrict__ out) {
    const int i = blockIdx.x * 256 + threadIdx.x;
    if (i >= N_NODES * OUT_DIM) return;
    const float dnm = denom[i >> 5];
    out[i] = (dnm > 0.f) ? out[i] / dnm : 0.f;
}

extern "C" void kernel_launch(void* const* d_in, const int* in_sizes, int n_in,
                              void* d_out, int out_size, void* d_ws, size_t ws_size,
                              hipStream_t stream) {
    const float* h      = (const float*)d_in[0];
    const int*   src    = (const int*)d_in[1];
    const int*   dst    = (const int*)d_in[2];
    const float* fc_w   = (const float*)d_in[3];
    const float* attn_w = (const float*)d_in[4];
    float* out = (float*)d_out;
    const int E = (in_sizes[1] > 0) ? in_sizes[1] : E_DEFAULT;
    const int nblk = (E + ECHUNK - 1) / ECHUNK;
    const int nblkp = (nblk + 7) & ~7;

    char* ws = (char*)d_ws;
    size_t off = 0;
    unsigned short* zbf = (unsigned short*)(ws + off);
    off += (size_t)N_NODES * OUT_DIM * sizeof(unsigned short);       // 6.4 MB
    float* s_l = (float*)(ws + off); off += (size_t)N_NODES * 4;     // 0.4 MB
    float* s_r = (float*)(ws + off); off += (size_t)N_NODES * 4;     // 0.4 MB

    const size_t base = off;
    int* packed = (int*)(ws + off);  off += (size_t)E * 4;           // 6.4 MB
    int* blkcnt = (int*)(ws + off);  off += (size_t)NB * nblkp * 4;  // ~0.63 MB
    int* bstart = (int*)(ws + off);  off += ((size_t)NB + 1) * 4;
    int* nstart = (int*)(ws + off);  off += ((size_t)NB * BUCKET_SIZE + 1) * 4;
    int* bsum   = (int*)(ws + off);  off += (size_t)NB * 4;
    const size_t csr_total = off;    // ~14.7 MB
    float* denom = (float*)(ws + base);

    const bool use_csr = (ws_size >= csr_total);

    if (use_csr) {
        const int waves = (N_NODES + 15) / 16;                 // 6250
        const int blocks_k1 = (waves + 3) / 4;                 // 1563
        k1_mfma<<<blocks_k1, 256, 0, stream>>>(h, fc_w, attn_w, zbf, s_l, s_r, bsum);
        k_hist2<<<nblk, 256, 0, stream>>>(dst, blkcnt, bsum, E, nblkp);
        k_scan_top<<<1, 1024, 0, stream>>>(bsum, bstart);
        k_scan_cols<<<(NB + 3) / 4, 256, 0, stream>>>(blkcnt, bstart, nblk, nblkp);
        k_scatter2<<<nblk, 256, 0, stream>>>(src, dst, blkcnt, packed, E, nblkp);
        k_place<<<NB, 256, 0, stream>>>(bstart, packed, nstart);
        const int blocks_g = (N_NODES * 64 + 255) / 256;
        k_gather8<<<blocks_g, 256, 0, stream>>>(nstart, packed, s_l, s_r, zbf, out);
    } else {
        const int blocks_k1 = (N_NODES + 255) / 256;
        k1_z_scores<<<blocks_k1, 256, 0, stream>>>(h, fc_w, attn_w, zbf, s_l, s_r, denom, out);
        const long long tot = (long long)E * 8;
        const int blocks_k3 = (int)((tot + 255) / 256);
        k3_edges<<<blocks_k3, 256, 0, stream>>>(src, dst, s_l, s_r, zbf, denom, out, E);
        const int blocks_k4 = (N_NODES * OUT_DIM + 255) / 256;
        k4_finalize<<<blocks_k4, 256, 0, stream>>>(denom, out);
    }
}